// Round 4
// baseline (2890.792 us; speedup 1.0000x reference)
//
#include <hip/hip_runtime.h>
#include <cstdint>
#include <cmath>
#include <cstring>
#include <vector>
#include <algorithm>
#include <utility>

// Problem constants (from reference)
#define KTOT 65536
#define PP   4096
#define DD   256
#define KMP  61440   // K - P
#define P2   2048    // P/2
#define BB   4096
#define NPB  512     // 65536/128 column blocks in stage-B GEMM

// ---------------------------------------------------------------------------
// Host-side replication of JAX threefry RNG under jax_threefry_partitionable
// (default True in modern JAX):
//   split(key)[j]          = threefry2x32(key, (0, j))   -- both output words
//   random_bits(key,32,n)i = a ^ b, (a,b) = threefry2x32(key, (0, i))
//   fold_in(key, d)        = threefry2x32(key, (0, d))   -- both output words
// ---------------------------------------------------------------------------
static inline void tf2x32(uint32_t k0, uint32_t k1, uint32_t x0, uint32_t x1,
                          uint32_t* o0, uint32_t* o1) {
  static const uint32_t rot[2][4] = {{13u,15u,26u,6u},{17u,29u,16u,24u}};
  uint32_t ks[3] = {k0, k1, 0x1BD11BDAu ^ k0 ^ k1};
  uint32_t v0 = x0 + ks[0], v1 = x1 + ks[1];
  for (int i = 0; i < 5; ++i) {
    const uint32_t* r = rot[i & 1];
    for (int j = 0; j < 4; ++j) {
      v0 += v1;
      v1 = (v1 << r[j]) | (v1 >> (32u - r[j]));
      v1 ^= v0;
    }
    v0 += ks[(i + 1) % 3];
    v1 += ks[(i + 2) % 3] + (uint32_t)(i + 1);
  }
  *o0 = v0; *o1 = v1;
}

static inline uint32_t tf_bits32(uint32_t k0, uint32_t k1, uint32_t i) {
  uint32_t a, b;
  tf2x32(k0, k1, 0u, i, &a, &b);
  return a ^ b;   // partitionable random_bits: XOR-fold the two halves
}

// Static host buffers: alive across graph replays (memcpy nodes re-read them).
static uint32_t h_mem_idx[KMP];
static uint32_t h_pos_in_mem[KTOT];
static uint32_t h_partsel[P2];     // part_idx[sel[k]] for k in [0,P2)

static void host_prepare() {
  // base = key(42) -> raw key (0, 42); key = fold_in(base, 0)
  uint32_t f0, f1; tf2x32(0u, 42u, 0u, 0u, &f0, &f1);
  // kperm, ksel = split(key)  (foldlike: child j = tf(key, (0, j)), both words)
  uint32_t kperm0, kperm1, ksel0, ksel1;
  tf2x32(f0, f1, 0u, 0u, &kperm0, &kperm1);
  tf2x32(f0, f1, 0u, 1u, &ksel0, &ksel1);

  // permutation(kperm, 65536): 2 rounds of stable sort by 32-bit random keys
  std::vector<uint32_t> perm(KTOT);
  for (uint32_t i = 0; i < KTOT; ++i) perm[i] = i;
  std::vector<std::pair<uint32_t,uint32_t>> kv(KTOT);
  uint32_t key0 = kperm0, key1 = kperm1;
  for (int round = 0; round < 2; ++round) {
    uint32_t nk0, nk1, sk0, sk1;
    tf2x32(key0, key1, 0u, 0u, &nk0, &nk1);   // key   = split(key)[0]
    tf2x32(key0, key1, 0u, 1u, &sk0, &sk1);   // subkey = split(key)[1]
    key0 = nk0; key1 = nk1;
    for (uint32_t i = 0; i < KTOT; ++i) {
      kv[i].first  = tf_bits32(sk0, sk1, i);
      kv[i].second = perm[i];
    }
    std::stable_sort(kv.begin(), kv.end(),
        [](const std::pair<uint32_t,uint32_t>& a,
           const std::pair<uint32_t,uint32_t>& b){ return a.first < b.first; });
    for (uint32_t i = 0; i < KTOT; ++i) perm[i] = kv[i].second;
  }
  static uint32_t part_idx[PP];
  for (int i = 0; i < PP;  ++i) part_idx[i] = perm[i];
  for (int i = 0; i < KMP; ++i) h_mem_idx[i] = perm[PP + i];
  for (int i = 0; i < KTOT; ++i) h_pos_in_mem[i] = 0xFFFFFFFFu;
  for (uint32_t c = 0; c < KMP; ++c) h_pos_in_mem[h_mem_idx[c]] = c;

  // gumbel(ksel, (4096,)); weights are constant to sub-f32-ulp (m>0 always),
  // so sel = top-2048 of (L0 + gumbel), ties -> lower index (lax.top_k)
  static float sval[PP];
  float c1f = (float)(1.0 + 1.0/(4.0*(double)KMP));
  float L0  = logf(1.0f / c1f);
  for (uint32_t i = 0; i < PP; ++i) {
    uint32_t bits = tf_bits32(ksel0, ksel1, i);
    uint32_t fb = (bits >> 9) | 0x3F800000u;
    float f; memcpy(&f, &fb, 4);
    f -= 1.0f;                                    // uniform in [0, 1-2^-23]
    float u = (f == 0.0f) ? 1.17549435e-38f : f;  // minval = tiny
    float g = -logf(-logf(u));
    sval[i] = L0 + g;
  }
  static uint32_t order[PP];
  for (uint32_t i = 0; i < PP; ++i) order[i] = i;
  std::sort(order, order + PP, [](uint32_t a, uint32_t b){
    if (sval[a] != sval[b]) return sval[a] > sval[b];
    return a < b;
  });
  for (int k = 0; k < P2; ++k) h_partsel[k] = part_idx[order[k]];
}

// Run once at shared-library load: kernel_launch itself then does identical
// work on every call (no call-time branching, no host compute in the window).
static const bool _host_tables_ready = (host_prepare(), true);

// ---------------------------------------------------------------------------
// Device kernels
// ---------------------------------------------------------------------------

// AT[DD][P2] = queue[:, partsel]  (k-major A operand for the argmax GEMM)
__global__ __launch_bounds__(256)
void gather_AT(const float* __restrict__ queue, const uint32_t* __restrict__ psel,
               float* __restrict__ AT) {
  int d = blockIdx.x;
  for (int k = threadIdx.x; k < P2; k += 256)
    AT[(size_t)d * P2 + k] = queue[(size_t)d * KTOT + psel[k]];
}

__global__ __launch_bounds__(256)
void gather_pne(const float* __restrict__ queue, const uint32_t* __restrict__ g_idx,
                float* __restrict__ pneB) {
  int d = blockIdx.x;
  for (int r = threadIdx.x; r < PP; r += 256)
    pneB[(size_t)d * PP + r] = queue[(size_t)d * KTOT + g_idx[r]];
}

// in[BB][DD] -> out[DD][BB]  (row-major -> k-major)
__global__ __launch_bounds__(256)
void transpose_MD(const float* __restrict__ in, float* __restrict__ out) {
  __shared__ float t[32][33];
  int c = threadIdx.x & 31, r0 = threadIdx.x >> 5;
  int d0 = blockIdx.x * 32, m0 = blockIdx.y * 32;
#pragma unroll
  for (int i = 0; i < 4; ++i) {
    int r = r0 + i * 8;
    t[r][c] = in[(size_t)(m0 + r) * DD + d0 + c];
  }
  __syncthreads();
#pragma unroll
  for (int i = 0; i < 4; ++i) {
    int r = r0 + i * 8;
    out[(size_t)(d0 + r) * BB + m0 + c] = t[c][r];
  }
}

// Tiled f32 GEMM, both operands k-major:
//   C[m][n] = sum_k AT[k][m] * B[k][n],  tile 128x128, thread tile 8x8.
// Staging writes are contiguous b128 (2-way, free); A-frag reads broadcast
// over tx (free); B-frag reads at tx*4 / 64+tx*4 (contiguous phase, 2-way).
// ARGMAX: masked per-row argmax over columns (c = pos_in_mem[n], ties -> min c)
// else:   write F tile (ld = LDB).
template<int LDA, int LDB, bool ARGMAX>
__global__ __launch_bounds__(256)
void gemm_kt(const float* __restrict__ AT, const float* __restrict__ B,
             const uint32_t* __restrict__ pos_in_mem,
             float* __restrict__ Fo,
             float* __restrict__ pval, uint32_t* __restrict__ pidx) {
  __shared__ union SM {
    struct { float As[32][128]; float Bs[32][128]; } s;
    struct { float rv[128][16]; uint32_t ri[128][16]; } r;
  } sm;
  const int tid = threadIdx.x;
  const int tx = tid & 15, ty = tid >> 4;
  const int m0 = blockIdx.y * 128, n0 = blockIdx.x * 128;
  const int col = (tid & 31) * 4, r0 = tid >> 5;

  float acc[8][8];
#pragma unroll
  for (int i = 0; i < 8; ++i)
#pragma unroll
    for (int j = 0; j < 8; ++j) acc[i][j] = 0.0f;

  for (int k0 = 0; k0 < DD; k0 += 32) {
#pragma unroll
    for (int rr = 0; rr < 4; ++rr) {
      int kk = r0 + rr * 8;
      *(float4*)&sm.s.As[kk][col] =
          *(const float4*)&AT[(size_t)(k0 + kk) * LDA + m0 + col];
      *(float4*)&sm.s.Bs[kk][col] =
          *(const float4*)&B[(size_t)(k0 + kk) * LDB + n0 + col];
    }
    __syncthreads();
#pragma unroll
    for (int kk = 0; kk < 32; ++kk) {
      float a[8], b[8];
      *(float4*)&a[0] = *(const float4*)&sm.s.As[kk][ty * 8];
      *(float4*)&a[4] = *(const float4*)&sm.s.As[kk][ty * 8 + 4];
      *(float4*)&b[0] = *(const float4*)&sm.s.Bs[kk][tx * 4];
      *(float4*)&b[4] = *(const float4*)&sm.s.Bs[kk][64 + tx * 4];
#pragma unroll
      for (int i = 0; i < 8; ++i)
#pragma unroll
        for (int j = 0; j < 8; ++j)
          acc[i][j] = fmaf(a[i], b[j], acc[i][j]);
    }
    __syncthreads();
  }

  if constexpr (ARGMAX) {
    const int nbase = n0 + tx * 4;
    uint32_t carr[8];
#pragma unroll
    for (int j = 0; j < 4; ++j) {
      carr[j]     = pos_in_mem[nbase + j];
      carr[4 + j] = pos_in_mem[nbase + 64 + j];
    }
#pragma unroll
    for (int i = 0; i < 8; ++i) {
      float bv = -INFINITY; uint32_t bc = 0xFFFFFFFFu;
#pragma unroll
      for (int j = 0; j < 8; ++j) {
        uint32_t c = carr[j]; float v = acc[i][j];
        if (c != 0xFFFFFFFFu && (v > bv || (v == bv && c < bc))) { bv = v; bc = c; }
      }
      sm.r.rv[ty * 8 + i][tx] = bv; sm.r.ri[ty * 8 + i][tx] = bc;
    }
    __syncthreads();
    if (tid < 128) {
      float bv = -INFINITY; uint32_t bc = 0xFFFFFFFFu;
#pragma unroll
      for (int t = 0; t < 16; ++t) {
        float v = sm.r.rv[tid][t]; uint32_t c = sm.r.ri[tid][t];
        if (v > bv || (v == bv && c < bc)) { bv = v; bc = c; }
      }
      pval[(size_t)(m0 + tid) * NPB + blockIdx.x] = bv;
      pidx[(size_t)(m0 + tid) * NPB + blockIdx.x] = bc;
    }
  } else {
#pragma unroll
    for (int i = 0; i < 8; ++i) {
      float4 o0, o1;
      o0.x = acc[i][0]; o0.y = acc[i][1]; o0.z = acc[i][2]; o0.w = acc[i][3];
      o1.x = acc[i][4]; o1.y = acc[i][5]; o1.z = acc[i][6]; o1.w = acc[i][7];
      *(float4*)&Fo[(size_t)(m0 + ty * 8 + i) * LDB + n0 + tx * 4]      = o0;
      *(float4*)&Fo[(size_t)(m0 + ty * 8 + i) * LDB + n0 + 64 + tx * 4] = o1;
    }
  }
}

__global__ __launch_bounds__(256)
void argmax_reduce(const float* __restrict__ pval, const uint32_t* __restrict__ pidx,
                   float* __restrict__ nval, uint32_t* __restrict__ nc) {
  int p = blockIdx.x, tid = threadIdx.x;
  float bv = -INFINITY; uint32_t bc = 0xFFFFFFFFu;
  for (int b = tid; b < NPB; b += 256) {
    float v = pval[(size_t)p * NPB + b]; uint32_t c = pidx[(size_t)p * NPB + b];
    if (v > bv || (v == bv && c < bc)) { bv = v; bc = c; }
  }
  for (int off = 32; off > 0; off >>= 1) {
    float v = __shfl_down(bv, off); uint32_t c = __shfl_down(bc, off);
    if (v > bv || (v == bv && c < bc)) { bv = v; bc = c; }
  }
  __shared__ float sv[4]; __shared__ uint32_t sc[4];
  int wid = tid >> 6;
  if ((tid & 63) == 0) { sv[wid] = bv; sc[wid] = bc; }
  __syncthreads();
  if (tid == 0) {
    for (int w = 1; w < 4; ++w) {
      float v = sv[w]; uint32_t c = sc[w];
      if (v > bv || (v == bv && c < bc)) { bv = v; bc = c; }
    }
    nval[p] = bv; nc[p] = bc;
  }
}

__global__ __launch_bounds__(256)
void prep(const uint32_t* __restrict__ nc, const float* __restrict__ nval,
          const uint32_t* __restrict__ mem_idx, const uint32_t* __restrict__ partsel,
          uint32_t* __restrict__ g_idx, float* __restrict__ svp, float* __restrict__ dp) {
  int k = blockIdx.x * 256 + threadIdx.x;
  if (k >= P2) return;
  uint32_t c = nc[k];
  float sf0 = nval[k];
  float sf1 = 0.9f;                       // 1.0 - SMOOTH
  g_idx[2 * k]     = mem_idx[c];
  g_idx[2 * k + 1] = partsel[k];
  float sv0 = (1.0f - sf0) / 2047.0f;
  float sv1 = (1.0f - sf1) / 2047.0f;
  float rs0 = sf0 + 2047.0f * sv0;        // M row sum (==1 to 1e-7)
  float rs1 = sf1 + 2047.0f * sv1;
  svp[2 * k]     = sv0 / rs0;  dp[2 * k]     = (sf0 - sv0) / rs0;
  svp[2 * k + 1] = sv1 / rs1;  dp[2 * k + 1] = (sf1 - sv1) / rs1;
}

// One block per output row b: softmax over 4096 logits + structured-M epilogue.
__global__ __launch_bounds__(256)
void softmax_out(const float* __restrict__ F, const float* __restrict__ temp_ptr,
                 const float* __restrict__ svp, const float* __restrict__ dp,
                 float* __restrict__ out) {
  __shared__ float e[PP];
  __shared__ float red[256];
  int b = blockIdx.x, tid = threadIdx.x;
  float temp = temp_ptr[0];
  float lmax = -INFINITY;
  for (int r = tid; r < PP; r += 256) {
    float l = F[(size_t)b * PP + r] / temp;
    e[r] = l;
    lmax = fmaxf(lmax, l);
  }
  red[tid] = lmax; __syncthreads();
  for (int s = 128; s > 0; s >>= 1) {
    if (tid < s) red[tid] = fmaxf(red[tid], red[tid + s]);
    __syncthreads();
  }
  lmax = red[0]; __syncthreads();

  float z = 0.0f, sacc = 0.0f;
  for (int r = tid; r < PP; r += 256) {
    float ev = expf(e[r] - lmax);
    e[r] = ev;
    z += ev;
    sacc = fmaf(ev, svp[r], sacc);
  }
  red[tid] = z; __syncthreads();
  for (int s = 128; s > 0; s >>= 1) {
    if (tid < s) red[tid] += red[tid + s];
    __syncthreads();
  }
  z = red[0]; __syncthreads();
  red[tid] = sacc; __syncthreads();
  for (int s = 128; s > 0; s >>= 1) {
    if (tid < s) red[tid] += red[tid + s];
    __syncthreads();
  }
  sacc = red[0]; __syncthreads();

  float invz = 1.0f / z;
  for (int j = tid; j < P2; j += 256) {
    float v = sacc + e[2 * j] * dp[2 * j] + e[2 * j + 1] * dp[2 * j + 1];
    out[(size_t)b * P2 + j] = v * invz;
  }
}

// ---------------------------------------------------------------------------
// Workspace layout (bytes). F(64MB) region is reused: AT2 + argmax partials
// live inside it (dead before F is written). studentT/teacherT live in d_out
// (dead until the matching softmax writes that half). Total ~71.9 MiB.
// ---------------------------------------------------------------------------
#define OFF_F        0u
#define OFF_AT2      0u          // 2 MB
#define OFF_PVAL     2097152u    // 4 MB
#define OFF_PIDX     6291456u    // 4 MB
#define OFF_PNEB     67108864u   // 4 MB
#define OFF_SVP      71303168u   // 16 KB
#define OFF_DP       71319552u   // 16 KB
#define OFF_GIDX     71335936u   // 16 KB
#define OFF_NVAL     71352320u   // 8 KB
#define OFF_NC       71360512u   // 8 KB
#define OFF_UP_MEM   71368704u   // 240 KB
#define OFF_UP_POS   71614464u   // 256 KB
#define OFF_UP_PSEL  71876608u   // 8 KB -> end 71884800

extern "C" void kernel_launch(void* const* d_in, const int* in_sizes, int n_in,
                              void* d_out, int out_size, void* d_ws, size_t ws_size,
                              hipStream_t stream) {
  (void)in_sizes; (void)n_in; (void)out_size; (void)ws_size;
  (void)_host_tables_ready;
  const float* d_student = (const float*)d_in[0];
  const float* d_teacher = (const float*)d_in[1];
  const float* d_queue   = (const float*)d_in[2];
  const float* d_stemp   = (const float*)d_in[3];
  const float* d_ttemp   = (const float*)d_in[4];
  float* out = (float*)d_out;
  char* ws = (char*)d_ws;

  float*    F       = (float*)(ws + OFF_F);
  float*    AT2     = (float*)(ws + OFF_AT2);
  float*    pval    = (float*)(ws + OFF_PVAL);
  uint32_t* pidx    = (uint32_t*)(ws + OFF_PIDX);
  float*    pneB    = (float*)(ws + OFF_PNEB);
  float*    svp     = (float*)(ws + OFF_SVP);
  float*    dp      = (float*)(ws + OFF_DP);
  uint32_t* g_idx   = (uint32_t*)(ws + OFF_GIDX);
  float*    nval    = (float*)(ws + OFF_NVAL);
  uint32_t* nc      = (uint32_t*)(ws + OFF_NC);
  uint32_t* dMemIdx = (uint32_t*)(ws + OFF_UP_MEM);
  uint32_t* dPosMem = (uint32_t*)(ws + OFF_UP_POS);
  uint32_t* dPSel   = (uint32_t*)(ws + OFF_UP_PSEL);

  // d_out scratch: studentT in first half (dead before softmax1 writes it),
  // teacherT in second half (dead before softmax2 writes it).
  float* studentT = out;                        // 4 MB of the 32 MB half
  float* teacherT = out + (size_t)BB * P2;      // 4 MB of the second half

  hipMemcpyAsync(dMemIdx, h_mem_idx,    KMP  * sizeof(uint32_t), hipMemcpyHostToDevice, stream);
  hipMemcpyAsync(dPosMem, h_pos_in_mem, KTOT * sizeof(uint32_t), hipMemcpyHostToDevice, stream);
  hipMemcpyAsync(dPSel,   h_partsel,    P2   * sizeof(uint32_t), hipMemcpyHostToDevice, stream);

  // Stage B: argmax over part[:,sel].T @ mem   (M = 2048 selected rows only)
  gather_AT<<<DD, 256, 0, stream>>>(d_queue, dPSel, AT2);
  gemm_kt<P2, KTOT, true><<<dim3(NPB, P2 / 128), 256, 0, stream>>>(
      AT2, d_queue, dPosMem, nullptr, pval, pidx);
  argmax_reduce<<<P2, 256, 0, stream>>>(pval, pidx, nval, nc);
  prep<<<P2 / 256, 256, 0, stream>>>(nc, nval, dMemIdx, dPSel, g_idx, svp, dp);
  gather_pne<<<DD, 256, 0, stream>>>(d_queue, g_idx, pneB);

  // Stage D: logits -> softmax -> structured-M epilogue (x2)
  transpose_MD<<<dim3(DD / 32, BB / 32), 256, 0, stream>>>(d_student, studentT);
  transpose_MD<<<dim3(DD / 32, BB / 32), 256, 0, stream>>>(d_teacher, teacherT);

  gemm_kt<BB, PP, false><<<dim3(PP / 128, BB / 128), 256, 0, stream>>>(
      studentT, pneB, nullptr, F, nullptr, nullptr);
  softmax_out<<<BB, 256, 0, stream>>>(F, d_stemp, svp, dp, out);

  gemm_kt<BB, PP, false><<<dim3(PP / 128, BB / 128), 256, 0, stream>>>(
      teacherT, pneB, nullptr, F, nullptr, nullptr);
  softmax_out<<<BB, 256, 0, stream>>>(F, d_ttemp, svp, dp, out + (size_t)BB * P2);
}

// Round 5
// 1257.234 us; speedup vs baseline: 2.2993x; 2.2993x over previous
//
#include <hip/hip_runtime.h>
#include <cstdint>
#include <cmath>
#include <cstring>
#include <vector>
#include <algorithm>
#include <utility>

// Problem constants (from reference)
#define KTOT 65536
#define PP   4096
#define DD   256
#define KMP  61440   // K - P
#define P2   2048    // P/2
#define BB   4096
#define NPB  512     // 65536/128 column blocks in stage-B GEMM

// ---------------------------------------------------------------------------
// Host-side replication of JAX threefry RNG under jax_threefry_partitionable
// (default True in modern JAX):
//   split(key)[j]          = threefry2x32(key, (0, j))   -- both output words
//   random_bits(key,32,n)i = a ^ b, (a,b) = threefry2x32(key, (0, i))
//   fold_in(key, d)        = threefry2x32(key, (0, d))   -- both output words
// ---------------------------------------------------------------------------
static inline void tf2x32(uint32_t k0, uint32_t k1, uint32_t x0, uint32_t x1,
                          uint32_t* o0, uint32_t* o1) {
  static const uint32_t rot[2][4] = {{13u,15u,26u,6u},{17u,29u,16u,24u}};
  uint32_t ks[3] = {k0, k1, 0x1BD11BDAu ^ k0 ^ k1};
  uint32_t v0 = x0 + ks[0], v1 = x1 + ks[1];
  for (int i = 0; i < 5; ++i) {
    const uint32_t* r = rot[i & 1];
    for (int j = 0; j < 4; ++j) {
      v0 += v1;
      v1 = (v1 << r[j]) | (v1 >> (32u - r[j]));
      v1 ^= v0;
    }
    v0 += ks[(i + 1) % 3];
    v1 += ks[(i + 2) % 3] + (uint32_t)(i + 1);
  }
  *o0 = v0; *o1 = v1;
}

static inline uint32_t tf_bits32(uint32_t k0, uint32_t k1, uint32_t i) {
  uint32_t a, b;
  tf2x32(k0, k1, 0u, i, &a, &b);
  return a ^ b;   // partitionable random_bits: XOR-fold the two halves
}

// Static host buffers: alive across graph replays (memcpy nodes re-read them).
static uint32_t h_mem_idx[KMP];
static uint32_t h_pos_in_mem[KTOT];
static uint32_t h_partsel[P2];     // part_idx[sel[k]] for k in [0,P2)

static void host_prepare() {
  // base = key(42) -> raw key (0, 42); key = fold_in(base, 0)
  uint32_t f0, f1; tf2x32(0u, 42u, 0u, 0u, &f0, &f1);
  // kperm, ksel = split(key)  (foldlike: child j = tf(key, (0, j)), both words)
  uint32_t kperm0, kperm1, ksel0, ksel1;
  tf2x32(f0, f1, 0u, 0u, &kperm0, &kperm1);
  tf2x32(f0, f1, 0u, 1u, &ksel0, &ksel1);

  // permutation(kperm, 65536): 2 rounds of stable sort by 32-bit random keys
  std::vector<uint32_t> perm(KTOT);
  for (uint32_t i = 0; i < KTOT; ++i) perm[i] = i;
  std::vector<std::pair<uint32_t,uint32_t>> kv(KTOT);
  uint32_t key0 = kperm0, key1 = kperm1;
  for (int round = 0; round < 2; ++round) {
    uint32_t nk0, nk1, sk0, sk1;
    tf2x32(key0, key1, 0u, 0u, &nk0, &nk1);   // key   = split(key)[0]
    tf2x32(key0, key1, 0u, 1u, &sk0, &sk1);   // subkey = split(key)[1]
    key0 = nk0; key1 = nk1;
    for (uint32_t i = 0; i < KTOT; ++i) {
      kv[i].first  = tf_bits32(sk0, sk1, i);
      kv[i].second = perm[i];
    }
    std::stable_sort(kv.begin(), kv.end(),
        [](const std::pair<uint32_t,uint32_t>& a,
           const std::pair<uint32_t,uint32_t>& b){ return a.first < b.first; });
    for (uint32_t i = 0; i < KTOT; ++i) perm[i] = kv[i].second;
  }
  static uint32_t part_idx[PP];
  for (int i = 0; i < PP;  ++i) part_idx[i] = perm[i];
  for (int i = 0; i < KMP; ++i) h_mem_idx[i] = perm[PP + i];
  for (int i = 0; i < KTOT; ++i) h_pos_in_mem[i] = 0xFFFFFFFFu;
  for (uint32_t c = 0; c < KMP; ++c) h_pos_in_mem[h_mem_idx[c]] = c;

  // gumbel(ksel, (4096,)); weights are constant to sub-f32-ulp (m>0 always),
  // so sel = top-2048 of (L0 + gumbel), ties -> lower index (lax.top_k)
  static float sval[PP];
  float c1f = (float)(1.0 + 1.0/(4.0*(double)KMP));
  float L0  = logf(1.0f / c1f);
  for (uint32_t i = 0; i < PP; ++i) {
    uint32_t bits = tf_bits32(ksel0, ksel1, i);
    uint32_t fb = (bits >> 9) | 0x3F800000u;
    float f; memcpy(&f, &fb, 4);
    f -= 1.0f;                                    // uniform in [0, 1-2^-23]
    float u = (f == 0.0f) ? 1.17549435e-38f : f;  // minval = tiny
    float g = -logf(-logf(u));
    sval[i] = L0 + g;
  }
  static uint32_t order[PP];
  for (uint32_t i = 0; i < PP; ++i) order[i] = i;
  std::sort(order, order + PP, [](uint32_t a, uint32_t b){
    if (sval[a] != sval[b]) return sval[a] > sval[b];
    return a < b;
  });
  for (int k = 0; k < P2; ++k) h_partsel[k] = part_idx[order[k]];
}

// Run once at shared-library load: kernel_launch itself then does identical
// work on every call (no call-time branching, no host compute in the window).
static const bool _host_tables_ready = (host_prepare(), true);

// ---------------------------------------------------------------------------
// Device kernels
// ---------------------------------------------------------------------------

// A[P2][DD] = (queue[:, partsel]).T  row-major gather for stage-B A operand
__global__ __launch_bounds__(256)
void gather_A(const float* __restrict__ queue, const uint32_t* __restrict__ psel,
              float* __restrict__ A) {
  int p = blockIdx.x, d = threadIdx.x;
  A[p * DD + d] = queue[d * KTOT + (int)psel[p]];
}

__global__ __launch_bounds__(256)
void gather_pne(const float* __restrict__ queue, const uint32_t* __restrict__ g_idx,
                float* __restrict__ pneB) {
  int d = blockIdx.x;
  for (int r = threadIdx.x; r < PP; r += 256)
    pneB[d * PP + r] = queue[d * KTOT + (int)g_idx[r]];
}

// Tiled f32 GEMM: C(128x128 tile) = A(Mx256 row-major) * B(256xN row-major, ld=LDB)
// ARGMAX: masked per-row argmax over columns (c = pos_in_mem[g], ties -> min c)
// else:   write F tile.
// NOTE: int32 indexing throughout (round-4 lesson: size_t math -> VGPR 140,
// occupancy collapse, 76% stall; int32 -> VGPR 92, proven 47% of FMA floor).
template<int LDB, bool ARGMAX>
__global__ __launch_bounds__(256)
void gemm_tile(const float* __restrict__ A, const float* __restrict__ B,
               const uint32_t* __restrict__ pos_in_mem,
               float* __restrict__ Fo,
               float* __restrict__ pval, uint32_t* __restrict__ pidx) {
  __shared__ float As[32][132];   // [k][m], +4 pad keeps 16B align, cuts write conflicts
  __shared__ float Bs[32][128];   // [k][n]
  const int tid = threadIdx.x;
  const int tx = tid & 15, ty = tid >> 4;
  const int m0 = blockIdx.y * 128, n0 = blockIdx.x * 128;

  float acc[8][8];
#pragma unroll
  for (int i = 0; i < 8; ++i)
#pragma unroll
    for (int j = 0; j < 8; ++j) acc[i][j] = 0.0f;

  const int ar = tid >> 3;          // 0..31
  const int ac4 = (tid & 7) * 4;    // k offset
  const int bkr = tid >> 5;         // 0..7
  const int bnc = (tid & 31) * 4;   // n offset

  for (int k0 = 0; k0 < DD; k0 += 32) {
#pragma unroll
    for (int rr = 0; rr < 4; ++rr) {
      int m = ar + rr * 32;
      const float4 av = *(const float4*)(&A[(m0 + m) * DD + k0 + ac4]);
      As[ac4 + 0][m] = av.x; As[ac4 + 1][m] = av.y;
      As[ac4 + 2][m] = av.z; As[ac4 + 3][m] = av.w;
    }
#pragma unroll
    for (int rr = 0; rr < 4; ++rr) {
      int kk = bkr + rr * 8;
      *(float4*)(&Bs[kk][bnc]) = *(const float4*)(&B[(k0 + kk) * LDB + n0 + bnc]);
    }
    __syncthreads();
#pragma unroll
    for (int kk = 0; kk < 32; ++kk) {
      float a[8], b[8];
      *(float4*)(&a[0]) = *(const float4*)(&As[kk][ty * 8]);
      *(float4*)(&a[4]) = *(const float4*)(&As[kk][ty * 8 + 4]);
      *(float4*)(&b[0]) = *(const float4*)(&Bs[kk][tx * 8]);
      *(float4*)(&b[4]) = *(const float4*)(&Bs[kk][tx * 8 + 4]);
#pragma unroll
      for (int i = 0; i < 8; ++i)
#pragma unroll
        for (int j = 0; j < 8; ++j)
          acc[i][j] = fmaf(a[i], b[j], acc[i][j]);
    }
    __syncthreads();
  }

  if constexpr (ARGMAX) {
    __shared__ float    rv[128][16];
    __shared__ uint32_t ri[128][16];
    const int nbase = n0 + tx * 8;
    uint32_t carr[8];
#pragma unroll
    for (int j = 0; j < 8; ++j) carr[j] = pos_in_mem[nbase + j];
#pragma unroll
    for (int i = 0; i < 8; ++i) {
      float bv = -INFINITY; uint32_t bc = 0xFFFFFFFFu;
#pragma unroll
      for (int j = 0; j < 8; ++j) {
        uint32_t c = carr[j]; float v = acc[i][j];
        if (c != 0xFFFFFFFFu && (v > bv || (v == bv && c < bc))) { bv = v; bc = c; }
      }
      rv[ty * 8 + i][tx] = bv; ri[ty * 8 + i][tx] = bc;
    }
    __syncthreads();
    if (tid < 128) {
      float bv = -INFINITY; uint32_t bc = 0xFFFFFFFFu;
#pragma unroll
      for (int t = 0; t < 16; ++t) {
        float v = rv[tid][t]; uint32_t c = ri[tid][t];
        if (v > bv || (v == bv && c < bc)) { bv = v; bc = c; }
      }
      pval[(m0 + tid) * NPB + blockIdx.x] = bv;
      pidx[(m0 + tid) * NPB + blockIdx.x] = bc;
    }
  } else {
#pragma unroll
    for (int i = 0; i < 8; ++i) {
      float4 o;
      o.x = acc[i][0]; o.y = acc[i][1]; o.z = acc[i][2]; o.w = acc[i][3];
      *(float4*)(&Fo[(m0 + ty * 8 + i) * LDB + n0 + tx * 8]) = o;
      o.x = acc[i][4]; o.y = acc[i][5]; o.z = acc[i][6]; o.w = acc[i][7];
      *(float4*)(&Fo[(m0 + ty * 8 + i) * LDB + n0 + tx * 8 + 4]) = o;
    }
  }
}

__global__ __launch_bounds__(256)
void argmax_reduce(const float* __restrict__ pval, const uint32_t* __restrict__ pidx,
                   float* __restrict__ nval, uint32_t* __restrict__ nc) {
  int p = blockIdx.x, tid = threadIdx.x;
  float bv = -INFINITY; uint32_t bc = 0xFFFFFFFFu;
  for (int b = tid; b < NPB; b += 256) {
    float v = pval[p * NPB + b]; uint32_t c = pidx[p * NPB + b];
    if (v > bv || (v == bv && c < bc)) { bv = v; bc = c; }
  }
  for (int off = 32; off > 0; off >>= 1) {
    float v = __shfl_down(bv, off); uint32_t c = __shfl_down(bc, off);
    if (v > bv || (v == bv && c < bc)) { bv = v; bc = c; }
  }
  __shared__ float sv[4]; __shared__ uint32_t sc[4];
  int wid = tid >> 6;
  if ((tid & 63) == 0) { sv[wid] = bv; sc[wid] = bc; }
  __syncthreads();
  if (tid == 0) {
    for (int w = 1; w < 4; ++w) {
      float v = sv[w]; uint32_t c = sc[w];
      if (v > bv || (v == bv && c < bc)) { bv = v; bc = c; }
    }
    nval[p] = bv; nc[p] = bc;
  }
}

__global__ __launch_bounds__(256)
void prep(const uint32_t* __restrict__ nc, const float* __restrict__ nval,
          const uint32_t* __restrict__ mem_idx, const uint32_t* __restrict__ partsel,
          uint32_t* __restrict__ g_idx, float* __restrict__ svp, float* __restrict__ dp) {
  int k = blockIdx.x * 256 + threadIdx.x;
  if (k >= P2) return;
  uint32_t c = nc[k];
  float sf0 = nval[k];
  float sf1 = 0.9f;                       // 1.0 - SMOOTH
  g_idx[2 * k]     = mem_idx[c];
  g_idx[2 * k + 1] = partsel[k];
  float sv0 = (1.0f - sf0) / 2047.0f;
  float sv1 = (1.0f - sf1) / 2047.0f;
  float rs0 = sf0 + 2047.0f * sv0;        // M row sum (==1 to 1e-7)
  float rs1 = sf1 + 2047.0f * sv1;
  svp[2 * k]     = sv0 / rs0;  dp[2 * k]     = (sf0 - sv0) / rs0;
  svp[2 * k + 1] = sv1 / rs1;  dp[2 * k + 1] = (sf1 - sv1) / rs1;
}

// One block per output row b: softmax over 4096 logits + structured-M epilogue.
__global__ __launch_bounds__(256)
void softmax_out(const float* __restrict__ F, const float* __restrict__ temp_ptr,
                 const float* __restrict__ svp, const float* __restrict__ dp,
                 float* __restrict__ out) {
  __shared__ float e[PP];
  __shared__ float red[256];
  int b = blockIdx.x, tid = threadIdx.x;
  float temp = temp_ptr[0];
  float lmax = -INFINITY;
  for (int r = tid; r < PP; r += 256) {
    float l = F[b * PP + r] / temp;
    e[r] = l;
    lmax = fmaxf(lmax, l);
  }
  red[tid] = lmax; __syncthreads();
  for (int s = 128; s > 0; s >>= 1) {
    if (tid < s) red[tid] = fmaxf(red[tid], red[tid + s]);
    __syncthreads();
  }
  lmax = red[0]; __syncthreads();

  float z = 0.0f, sacc = 0.0f;
  for (int r = tid; r < PP; r += 256) {
    float ev = expf(e[r] - lmax);
    e[r] = ev;
    z += ev;
    sacc = fmaf(ev, svp[r], sacc);
  }
  red[tid] = z; __syncthreads();
  for (int s = 128; s > 0; s >>= 1) {
    if (tid < s) red[tid] += red[tid + s];
    __syncthreads();
  }
  z = red[0]; __syncthreads();
  red[tid] = sacc; __syncthreads();
  for (int s = 128; s > 0; s >>= 1) {
    if (tid < s) red[tid] += red[tid + s];
    __syncthreads();
  }
  sacc = red[0]; __syncthreads();

  float invz = 1.0f / z;
  for (int j = tid; j < P2; j += 256) {
    float v = sacc + e[2 * j] * dp[2 * j] + e[2 * j + 1] * dp[2 * j + 1];
    out[b * P2 + j] = v * invz;
  }
}

// ---------------------------------------------------------------------------
// Workspace layout (bytes). F(64MB) region is reused: Apart + argmax partials
// live inside it (dead before F is written). Total ~71.9 MiB.
// ---------------------------------------------------------------------------
#define OFF_F        0u
#define OFF_APART    0u          // 2 MB (2048 x 256 f32)
#define OFF_PVAL     2097152u    // 4 MB
#define OFF_PIDX     6291456u    // 4 MB
#define OFF_PNEB     67108864u   // 4 MB
#define OFF_SVP      71303168u   // 16 KB
#define OFF_DP       71319552u   // 16 KB
#define OFF_GIDX     71335936u   // 16 KB
#define OFF_NVAL     71352320u   // 8 KB
#define OFF_NC       71360512u   // 8 KB
#define OFF_UP_MEM   71368704u   // 240 KB
#define OFF_UP_POS   71614464u   // 256 KB
#define OFF_UP_PSEL  71876608u   // 8 KB -> end 71884800

extern "C" void kernel_launch(void* const* d_in, const int* in_sizes, int n_in,
                              void* d_out, int out_size, void* d_ws, size_t ws_size,
                              hipStream_t stream) {
  (void)in_sizes; (void)n_in; (void)out_size; (void)ws_size;
  (void)_host_tables_ready;
  const float* d_student = (const float*)d_in[0];
  const float* d_teacher = (const float*)d_in[1];
  const float* d_queue   = (const float*)d_in[2];
  const float* d_stemp   = (const float*)d_in[3];
  const float* d_ttemp   = (const float*)d_in[4];
  float* out = (float*)d_out;
  char* ws = (char*)d_ws;

  float*    F       = (float*)(ws + OFF_F);
  float*    Apart   = (float*)(ws + OFF_APART);
  float*    pval    = (float*)(ws + OFF_PVAL);
  uint32_t* pidx    = (uint32_t*)(ws + OFF_PIDX);
  float*    pneB    = (float*)(ws + OFF_PNEB);
  float*    svp     = (float*)(ws + OFF_SVP);
  float*    dp      = (float*)(ws + OFF_DP);
  uint32_t* g_idx   = (uint32_t*)(ws + OFF_GIDX);
  float*    nval    = (float*)(ws + OFF_NVAL);
  uint32_t* nc      = (uint32_t*)(ws + OFF_NC);
  uint32_t* dMemIdx = (uint32_t*)(ws + OFF_UP_MEM);
  uint32_t* dPosMem = (uint32_t*)(ws + OFF_UP_POS);
  uint32_t* dPSel   = (uint32_t*)(ws + OFF_UP_PSEL);

  hipMemcpyAsync(dMemIdx, h_mem_idx,    KMP  * sizeof(uint32_t), hipMemcpyHostToDevice, stream);
  hipMemcpyAsync(dPosMem, h_pos_in_mem, KTOT * sizeof(uint32_t), hipMemcpyHostToDevice, stream);
  hipMemcpyAsync(dPSel,   h_partsel,    P2   * sizeof(uint32_t), hipMemcpyHostToDevice, stream);

  // Stage B: argmax over part[:,sel].T @ mem   (M = 2048 selected rows only)
  gather_A<<<P2, 256, 0, stream>>>(d_queue, dPSel, Apart);
  gemm_tile<KTOT, true><<<dim3(NPB, P2 / 128), 256, 0, stream>>>(
      Apart, d_queue, dPosMem, nullptr, pval, pidx);
  argmax_reduce<<<P2, 256, 0, stream>>>(pval, pidx, nval, nc);
  prep<<<P2 / 256, 256, 0, stream>>>(nc, nval, dMemIdx, dPSel, g_idx, svp, dp);
  gather_pne<<<DD, 256, 0, stream>>>(d_queue, g_idx, pneB);

  // Stage D: logits -> softmax -> structured-M epilogue (x2)
  gemm_tile<PP, false><<<dim3(PP / 128, BB / 128), 256, 0, stream>>>(
      d_student, pneB, nullptr, F, nullptr, nullptr);
  softmax_out<<<BB, 256, 0, stream>>>(F, d_stemp, svp, dp, out);

  gemm_tile<PP, false><<<dim3(PP / 128, BB / 128), 256, 0, stream>>>(
      d_teacher, pneB, nullptr, F, nullptr, nullptr);
  softmax_out<<<BB, 256, 0, stream>>>(F, d_ttemp, svp, dp, out + (size_t)BB * P2);
}

// Round 6
// 759.451 us; speedup vs baseline: 3.8064x; 1.6555x over previous
//
#include <hip/hip_runtime.h>
#include <cstdint>
#include <cmath>
#include <cstring>
#include <vector>
#include <algorithm>
#include <utility>

// Problem constants (from reference)
#define KTOT 65536
#define PP   4096
#define DD   256
#define KMP  61440   // K - P
#define P2   2048    // P/2
#define BB   4096
#define NPB  512     // 65536/128 column blocks in stage-B GEMM
#define INVALID_C 0xFFFFFFFFu

// ---------------------------------------------------------------------------
// Host-side replication of JAX threefry RNG under jax_threefry_partitionable
// ---------------------------------------------------------------------------
static inline void tf2x32(uint32_t k0, uint32_t k1, uint32_t x0, uint32_t x1,
                          uint32_t* o0, uint32_t* o1) {
  static const uint32_t rot[2][4] = {{13u,15u,26u,6u},{17u,29u,16u,24u}};
  uint32_t ks[3] = {k0, k1, 0x1BD11BDAu ^ k0 ^ k1};
  uint32_t v0 = x0 + ks[0], v1 = x1 + ks[1];
  for (int i = 0; i < 5; ++i) {
    const uint32_t* r = rot[i & 1];
    for (int j = 0; j < 4; ++j) {
      v0 += v1;
      v1 = (v1 << r[j]) | (v1 >> (32u - r[j]));
      v1 ^= v0;
    }
    v0 += ks[(i + 1) % 3];
    v1 += ks[(i + 2) % 3] + (uint32_t)(i + 1);
  }
  *o0 = v0; *o1 = v1;
}

static inline uint32_t tf_bits32(uint32_t k0, uint32_t k1, uint32_t i) {
  uint32_t a, b;
  tf2x32(k0, k1, 0u, i, &a, &b);
  return a ^ b;   // partitionable random_bits: XOR-fold the two halves
}

static uint32_t h_mem_idx[KMP];
static uint32_t h_pos_in_mem[KTOT];
static uint32_t h_partsel[P2];     // part_idx[sel[k]] for k in [0,P2)

static void host_prepare() {
  uint32_t f0, f1; tf2x32(0u, 42u, 0u, 0u, &f0, &f1);
  uint32_t kperm0, kperm1, ksel0, ksel1;
  tf2x32(f0, f1, 0u, 0u, &kperm0, &kperm1);
  tf2x32(f0, f1, 0u, 1u, &ksel0, &ksel1);

  std::vector<uint32_t> perm(KTOT);
  for (uint32_t i = 0; i < KTOT; ++i) perm[i] = i;
  std::vector<std::pair<uint32_t,uint32_t>> kv(KTOT);
  uint32_t key0 = kperm0, key1 = kperm1;
  for (int round = 0; round < 2; ++round) {
    uint32_t nk0, nk1, sk0, sk1;
    tf2x32(key0, key1, 0u, 0u, &nk0, &nk1);
    tf2x32(key0, key1, 0u, 1u, &sk0, &sk1);
    key0 = nk0; key1 = nk1;
    for (uint32_t i = 0; i < KTOT; ++i) {
      kv[i].first  = tf_bits32(sk0, sk1, i);
      kv[i].second = perm[i];
    }
    std::stable_sort(kv.begin(), kv.end(),
        [](const std::pair<uint32_t,uint32_t>& a,
           const std::pair<uint32_t,uint32_t>& b){ return a.first < b.first; });
    for (uint32_t i = 0; i < KTOT; ++i) perm[i] = kv[i].second;
  }
  static uint32_t part_idx[PP];
  for (int i = 0; i < PP;  ++i) part_idx[i] = perm[i];
  for (int i = 0; i < KMP; ++i) h_mem_idx[i] = perm[PP + i];
  for (int i = 0; i < KTOT; ++i) h_pos_in_mem[i] = INVALID_C;
  for (uint32_t c = 0; c < KMP; ++c) h_pos_in_mem[h_mem_idx[c]] = c;

  static float sval[PP];
  float c1f = (float)(1.0 + 1.0/(4.0*(double)KMP));
  float L0  = logf(1.0f / c1f);
  for (uint32_t i = 0; i < PP; ++i) {
    uint32_t bits = tf_bits32(ksel0, ksel1, i);
    uint32_t fb = (bits >> 9) | 0x3F800000u;
    float f; memcpy(&f, &fb, 4);
    f -= 1.0f;
    float u = (f == 0.0f) ? 1.17549435e-38f : f;
    float g = -logf(-logf(u));
    sval[i] = L0 + g;
  }
  static uint32_t order[PP];
  for (uint32_t i = 0; i < PP; ++i) order[i] = i;
  std::sort(order, order + PP, [](uint32_t a, uint32_t b){
    if (sval[a] != sval[b]) return sval[a] > sval[b];
    return a < b;
  });
  for (int k = 0; k < P2; ++k) h_partsel[k] = part_idx[order[k]];
}

static const bool _host_tables_ready = (host_prepare(), true);

// ---------------------------------------------------------------------------
// Device helpers / kernels
// ---------------------------------------------------------------------------
typedef __attribute__((ext_vector_type(8))) short bf16x8;
typedef __attribute__((ext_vector_type(4))) float f32x4;

__device__ inline unsigned short f2bf(float x) {
  union { float f; uint32_t u; } v; v.f = x;
  return (unsigned short)((v.u + 0x7FFFu + ((v.u >> 16) & 1u)) >> 16);
}

// queue f32 [256][65536] -> BhT bf16 [65536][256]  (transpose + convert)
__global__ __launch_bounds__(256)
void transpose_bf16(const float* __restrict__ queue, unsigned short* __restrict__ BhT) {
  __shared__ float t[64][65];
  const int tid = threadIdx.x;
  const int c4 = (tid & 15) * 4, r = tid >> 4;   // r in 0..15
  const int n0 = blockIdx.x * 64, d0 = blockIdx.y * 64;
#pragma unroll
  for (int i = 0; i < 4; ++i) {
    int d = r + i * 16;
    float4 v = *(const float4*)&queue[(d0 + d) * KTOT + n0 + c4];
    t[d][c4 + 0] = v.x; t[d][c4 + 1] = v.y; t[d][c4 + 2] = v.z; t[d][c4 + 3] = v.w;
  }
  __syncthreads();
#pragma unroll
  for (int i = 0; i < 4; ++i) {
    int n = r + i * 16;
    uint32_t lo = (uint32_t)f2bf(t[c4 + 0][n]) | ((uint32_t)f2bf(t[c4 + 1][n]) << 16);
    uint32_t hi = (uint32_t)f2bf(t[c4 + 2][n]) | ((uint32_t)f2bf(t[c4 + 3][n]) << 16);
    uint2 w; w.x = lo; w.y = hi;
    *(uint2*)&BhT[(n0 + n) * DD + d0 + c4] = w;
  }
}

// Apart f32 [2048][256] + AhT bf16 [2048][256] = (queue[:, partsel]).T
__global__ __launch_bounds__(256)
void gather_A(const float* __restrict__ queue, const uint32_t* __restrict__ psel,
              float* __restrict__ Apart, unsigned short* __restrict__ AhT) {
  int p = blockIdx.x, d = threadIdx.x;
  float q = queue[d * KTOT + (int)psel[p]];
  Apart[p * DD + d] = q;
  AhT[p * DD + d] = f2bf(q);
}

__global__ __launch_bounds__(256)
void gather_pne(const float* __restrict__ queue, const uint32_t* __restrict__ g_idx,
                float* __restrict__ pneB) {
  int d = blockIdx.x;
  for (int r = threadIdx.x; r < PP; r += 256)
    pneB[d * PP + r] = queue[d * KTOT + (int)g_idx[r]];
}

// ---------------------------------------------------------------------------
// Stage B: bf16 MFMA GEMM (2048 x 65536 x 256) with per-block top-2 epilogue.
// Layouts (learn_hip verified): A[m=lane&15][k=quad*8+j]; B[k=quad*8+j][n=lane&15];
// D col=lane&15, row=quad*4+reg. Tiles: 128x128 per block, 64x64 per wave.
// LDS: [row][k] with row stride 40 bf16 (80 B) -> b128 reads are 2-way (free).
// ---------------------------------------------------------------------------
__global__ __launch_bounds__(256)
void mfma_argmax(const unsigned short* __restrict__ AhT,   // [2048][256]
                 const unsigned short* __restrict__ BhT,   // [65536][256]
                 const uint32_t* __restrict__ pos_in_mem,
                 float* __restrict__ pv2, uint32_t* __restrict__ pc2) {
  __shared__ union SM {
    struct { unsigned short As[128][40]; unsigned short Bs[128][40]; } s;  // 20 KB
    struct { float rv[128][32]; uint32_t ri[128][32]; } r;                 // 32 KB
  } sm;
  const int tid = threadIdx.x;
  const int m0 = blockIdx.y * 128, n0 = blockIdx.x * 128;
  const int wave = tid >> 6, lane = tid & 63;
  const int wm = (wave >> 1) * 64, wn = (wave & 1) * 64;
  const int l15 = lane & 15, quad = lane >> 4;

  f32x4 acc[4][4];
#pragma unroll
  for (int i = 0; i < 4; ++i)
#pragma unroll
    for (int j = 0; j < 4; ++j) acc[i][j] = (f32x4){0.f, 0.f, 0.f, 0.f};

  const int arow = tid >> 2;          // 0..63
  const int koff = (tid & 3) * 8;     // 0,8,16,24

  for (int k0 = 0; k0 < DD; k0 += 32) {
    *(uint4*)&sm.s.As[arow][koff]      = *(const uint4*)&AhT[(m0 + arow) * DD + k0 + koff];
    *(uint4*)&sm.s.As[arow + 64][koff] = *(const uint4*)&AhT[(m0 + arow + 64) * DD + k0 + koff];
    *(uint4*)&sm.s.Bs[arow][koff]      = *(const uint4*)&BhT[(n0 + arow) * DD + k0 + koff];
    *(uint4*)&sm.s.Bs[arow + 64][koff] = *(const uint4*)&BhT[(n0 + arow + 64) * DD + k0 + koff];
    __syncthreads();
    bf16x8 a[4], b[4];
#pragma unroll
    for (int i = 0; i < 4; ++i)
      a[i] = *(const bf16x8*)&sm.s.As[wm + i * 16 + l15][quad * 8];
#pragma unroll
    for (int j = 0; j < 4; ++j)
      b[j] = *(const bf16x8*)&sm.s.Bs[wn + j * 16 + l15][quad * 8];
#pragma unroll
    for (int i = 0; i < 4; ++i)
#pragma unroll
      for (int j = 0; j < 4; ++j)
        acc[i][j] = __builtin_amdgcn_mfma_f32_16x16x32_bf16(a[i], b[j], acc[i][j], 0, 0, 0);
    __syncthreads();
  }

  // Epilogue: per-lane max over its 4 cols, then per-row top-2 over 32 slots.
  uint32_t carr[4];
#pragma unroll
  for (int j = 0; j < 4; ++j) carr[j] = pos_in_mem[n0 + wn + j * 16 + l15];
#pragma unroll
  for (int i = 0; i < 4; ++i)
#pragma unroll
    for (int r = 0; r < 4; ++r) {
      float bv = -INFINITY; uint32_t bc = INVALID_C;
#pragma unroll
      for (int j = 0; j < 4; ++j) {
        float v = acc[i][j][r]; uint32_t c = carr[j];
        if (c != INVALID_C && (v > bv || (v == bv && c < bc))) { bv = v; bc = c; }
      }
      int row = wm + i * 16 + quad * 4 + r;
      sm.r.rv[row][(wave & 1) * 16 + l15] = bv;
      sm.r.ri[row][(wave & 1) * 16 + l15] = bc;
    }
  __syncthreads();
  if (tid < 128) {
    float v1 = -INFINITY, v2 = -INFINITY; uint32_t c1 = INVALID_C, c2 = INVALID_C;
#pragma unroll 4
    for (int s = 0; s < 32; ++s) {
      float v = sm.r.rv[tid][s]; uint32_t c = sm.r.ri[tid][s];
      if (c == INVALID_C) continue;
      if (v > v1 || (v == v1 && c < c1)) { v2 = v1; c2 = c1; v1 = v; c1 = c; }
      else if (v > v2 || (v == v2 && c < c2)) { v2 = v; c2 = c; }
    }
    int base = (m0 + tid) * (NPB * 2) + blockIdx.x * 2;
    pv2[base] = v1;     pc2[base] = c1;
    pv2[base + 1] = v2; pc2[base + 1] = c2;
  }
}

// Per row: global max over 1024 (block,slot) entries; all entries within EPS
// are exactly rescored in f32 (bf16 error <= 2^-8 * ||a||*||b|| = 3.9e-3 < EPS/2).
#define EPS_W 0.01f
__global__ __launch_bounds__(256)
void argmax_rescore(const float* __restrict__ pv2, const uint32_t* __restrict__ pc2,
                    const float* __restrict__ Apart, const float* __restrict__ queue,
                    const uint32_t* __restrict__ mem_idx,
                    float* __restrict__ nval, uint32_t* __restrict__ nc) {
  __shared__ float red[256];
  __shared__ uint32_t cand[32];
  __shared__ int cnt;
  const int row = blockIdx.x, tid = threadIdx.x;

  float m = -INFINITY;
  for (int e = tid; e < NPB * 2; e += 256) m = fmaxf(m, pv2[row * (NPB * 2) + e]);
  red[tid] = m; __syncthreads();
  for (int s = 128; s > 0; s >>= 1) {
    if (tid < s) red[tid] = fmaxf(red[tid], red[tid + s]);
    __syncthreads();
  }
  const float M = red[0];
  if (tid == 0) cnt = 0;
  __syncthreads();
  for (int e = tid; e < NPB * 2; e += 256) {
    float v = pv2[row * (NPB * 2) + e]; uint32_t c = pc2[row * (NPB * 2) + e];
    if (c != INVALID_C && v >= M - EPS_W) {
      int k = atomicAdd(&cnt, 1);
      if (k < 32) cand[k] = c;
    }
  }
  __syncthreads();
  const int ncand = min(cnt, 32);
  __shared__ float bestv_s; __shared__ uint32_t bestc_s;
  if (tid == 0) { bestv_s = -INFINITY; bestc_s = INVALID_C; }
  __syncthreads();
  const float av = Apart[row * DD + tid];
  for (int k = 0; k < ncand; ++k) {
    uint32_t c = cand[k];
    int n = (int)mem_idx[c];
    red[tid] = av * queue[tid * KTOT + n];
    __syncthreads();
    for (int s = 128; s > 0; s >>= 1) {
      if (tid < s) red[tid] += red[tid + s];
      __syncthreads();
    }
    if (tid == 0) {
      float sc = red[0];
      if (sc > bestv_s || (sc == bestv_s && c < bestc_s)) { bestv_s = sc; bestc_s = c; }
    }
    __syncthreads();
  }
  if (tid == 0) { nval[row] = bestv_s; nc[row] = bestc_s; }
}

// ---------------------------------------------------------------------------
// Stage D: proven round-5 f32 GEMM (F tile write path only) + softmax.
// int32 indexing (round-4 lesson: size_t math -> occupancy collapse).
// ---------------------------------------------------------------------------
__global__ __launch_bounds__(256)
void gemm_f(const float* __restrict__ A, const float* __restrict__ B,
            float* __restrict__ Fo) {
  __shared__ float As[32][132];
  __shared__ float Bs[32][128];
  const int tid = threadIdx.x;
  const int tx = tid & 15, ty = tid >> 4;
  const int m0 = blockIdx.y * 128, n0 = blockIdx.x * 128;

  float acc[8][8];
#pragma unroll
  for (int i = 0; i < 8; ++i)
#pragma unroll
    for (int j = 0; j < 8; ++j) acc[i][j] = 0.0f;

  const int ar = tid >> 3;
  const int ac4 = (tid & 7) * 4;
  const int bkr = tid >> 5;
  const int bnc = (tid & 31) * 4;

  for (int k0 = 0; k0 < DD; k0 += 32) {
#pragma unroll
    for (int rr = 0; rr < 4; ++rr) {
      int m = ar + rr * 32;
      const float4 av = *(const float4*)(&A[(m0 + m) * DD + k0 + ac4]);
      As[ac4 + 0][m] = av.x; As[ac4 + 1][m] = av.y;
      As[ac4 + 2][m] = av.z; As[ac4 + 3][m] = av.w;
    }
#pragma unroll
    for (int rr = 0; rr < 4; ++rr) {
      int kk = bkr + rr * 8;
      *(float4*)(&Bs[kk][bnc]) = *(const float4*)(&B[(k0 + kk) * PP + n0 + bnc]);
    }
    __syncthreads();
#pragma unroll
    for (int kk = 0; kk < 32; ++kk) {
      float a[8], b[8];
      *(float4*)(&a[0]) = *(const float4*)(&As[kk][ty * 8]);
      *(float4*)(&a[4]) = *(const float4*)(&As[kk][ty * 8 + 4]);
      *(float4*)(&b[0]) = *(const float4*)(&Bs[kk][tx * 8]);
      *(float4*)(&b[4]) = *(const float4*)(&Bs[kk][tx * 8 + 4]);
#pragma unroll
      for (int i = 0; i < 8; ++i)
#pragma unroll
        for (int j = 0; j < 8; ++j)
          acc[i][j] = fmaf(a[i], b[j], acc[i][j]);
    }
    __syncthreads();
  }
#pragma unroll
  for (int i = 0; i < 8; ++i) {
    float4 o;
    o.x = acc[i][0]; o.y = acc[i][1]; o.z = acc[i][2]; o.w = acc[i][3];
    *(float4*)(&Fo[(m0 + ty * 8 + i) * PP + n0 + tx * 8]) = o;
    o.x = acc[i][4]; o.y = acc[i][5]; o.z = acc[i][6]; o.w = acc[i][7];
    *(float4*)(&Fo[(m0 + ty * 8 + i) * PP + n0 + tx * 8 + 4]) = o;
  }
}

__global__ __launch_bounds__(256)
void prep(const uint32_t* __restrict__ nc, const float* __restrict__ nval,
          const uint32_t* __restrict__ mem_idx, const uint32_t* __restrict__ partsel,
          uint32_t* __restrict__ g_idx, float* __restrict__ svp, float* __restrict__ dp) {
  int k = blockIdx.x * 256 + threadIdx.x;
  if (k >= P2) return;
  uint32_t c = nc[k];
  float sf0 = nval[k];
  float sf1 = 0.9f;                       // 1.0 - SMOOTH
  g_idx[2 * k]     = mem_idx[c];
  g_idx[2 * k + 1] = partsel[k];
  float sv0 = (1.0f - sf0) / 2047.0f;
  float sv1 = (1.0f - sf1) / 2047.0f;
  float rs0 = sf0 + 2047.0f * sv0;
  float rs1 = sf1 + 2047.0f * sv1;
  svp[2 * k]     = sv0 / rs0;  dp[2 * k]     = (sf0 - sv0) / rs0;
  svp[2 * k + 1] = sv1 / rs1;  dp[2 * k + 1] = (sf1 - sv1) / rs1;
}

__global__ __launch_bounds__(256)
void softmax_out(const float* __restrict__ F, const float* __restrict__ temp_ptr,
                 const float* __restrict__ svp, const float* __restrict__ dp,
                 float* __restrict__ out) {
  __shared__ float e[PP];
  __shared__ float red[256];
  int b = blockIdx.x, tid = threadIdx.x;
  float temp = temp_ptr[0];
  float lmax = -INFINITY;
  for (int r = tid; r < PP; r += 256) {
    float l = F[b * PP + r] / temp;
    e[r] = l;
    lmax = fmaxf(lmax, l);
  }
  red[tid] = lmax; __syncthreads();
  for (int s = 128; s > 0; s >>= 1) {
    if (tid < s) red[tid] = fmaxf(red[tid], red[tid + s]);
    __syncthreads();
  }
  lmax = red[0]; __syncthreads();

  float z = 0.0f, sacc = 0.0f;
  for (int r = tid; r < PP; r += 256) {
    float ev = expf(e[r] - lmax);
    e[r] = ev;
    z += ev;
    sacc = fmaf(ev, svp[r], sacc);
  }
  red[tid] = z; __syncthreads();
  for (int s = 128; s > 0; s >>= 1) {
    if (tid < s) red[tid] += red[tid + s];
    __syncthreads();
  }
  z = red[0]; __syncthreads();
  red[tid] = sacc; __syncthreads();
  for (int s = 128; s > 0; s >>= 1) {
    if (tid < s) red[tid] += red[tid + s];
    __syncthreads();
  }
  sacc = red[0]; __syncthreads();

  float invz = 1.0f / z;
  for (int j = tid; j < P2; j += 256) {
    float v = sacc + e[2 * j] * dp[2 * j] + e[2 * j + 1] * dp[2 * j + 1];
    out[b * P2 + j] = v * invz;
  }
}

// ---------------------------------------------------------------------------
// Workspace layout (bytes). Stage-B buffers (BhT/pv2/pc2/AhT/Apart) all live
// inside F's 64 MB region and are dead before stage D writes F. ~68.6 MiB.
// ---------------------------------------------------------------------------
#define OFF_BHT      0u          // 32 MB  (65536 x 256 bf16)
#define OFF_PV2      33554432u   // 8 MB   (2048 x 1024 f32)
#define OFF_PC2      41943040u   // 8 MB
#define OFF_AHT      50331648u   // 1 MB   (2048 x 256 bf16)
#define OFF_APART    51380224u   // 2 MB   (2048 x 256 f32)
#define OFF_F        0u          // 64 MB  (stage D; overlaps all of the above)
#define OFF_PNEB     67108864u   // 4 MB
#define OFF_SVP      71303168u   // 16 KB
#define OFF_DP       71319552u   // 16 KB
#define OFF_GIDX     71335936u   // 16 KB
#define OFF_NVAL     71352320u   // 8 KB
#define OFF_NC       71360512u   // 8 KB
#define OFF_UP_MEM   71368704u   // 240 KB
#define OFF_UP_POS   71614464u   // 256 KB
#define OFF_UP_PSEL  71876608u   // 8 KB -> end 71884800 (proven <= ws_size)

extern "C" void kernel_launch(void* const* d_in, const int* in_sizes, int n_in,
                              void* d_out, int out_size, void* d_ws, size_t ws_size,
                              hipStream_t stream) {
  (void)in_sizes; (void)n_in; (void)out_size; (void)ws_size;
  (void)_host_tables_ready;
  const float* d_student = (const float*)d_in[0];
  const float* d_teacher = (const float*)d_in[1];
  const float* d_queue   = (const float*)d_in[2];
  const float* d_stemp   = (const float*)d_in[3];
  const float* d_ttemp   = (const float*)d_in[4];
  float* out = (float*)d_out;
  char* ws = (char*)d_ws;

  unsigned short* BhT   = (unsigned short*)(ws + OFF_BHT);
  float*          pv2   = (float*)(ws + OFF_PV2);
  uint32_t*       pc2   = (uint32_t*)(ws + OFF_PC2);
  unsigned short* AhT   = (unsigned short*)(ws + OFF_AHT);
  float*          Apart = (float*)(ws + OFF_APART);
  float*          F     = (float*)(ws + OFF_F);
  float*          pneB  = (float*)(ws + OFF_PNEB);
  float*          svp   = (float*)(ws + OFF_SVP);
  float*          dp    = (float*)(ws + OFF_DP);
  uint32_t*       g_idx = (uint32_t*)(ws + OFF_GIDX);
  float*          nval  = (float*)(ws + OFF_NVAL);
  uint32_t*       nc    = (uint32_t*)(ws + OFF_NC);
  uint32_t*       dMemIdx = (uint32_t*)(ws + OFF_UP_MEM);
  uint32_t*       dPosMem = (uint32_t*)(ws + OFF_UP_POS);
  uint32_t*       dPSel   = (uint32_t*)(ws + OFF_UP_PSEL);

  hipMemcpyAsync(dMemIdx, h_mem_idx,    KMP  * sizeof(uint32_t), hipMemcpyHostToDevice, stream);
  hipMemcpyAsync(dPosMem, h_pos_in_mem, KTOT * sizeof(uint32_t), hipMemcpyHostToDevice, stream);
  hipMemcpyAsync(dPSel,   h_partsel,    P2   * sizeof(uint32_t), hipMemcpyHostToDevice, stream);

  // Stage B: bf16 MFMA scoring + exact f32 rescore of the epsilon-window
  transpose_bf16<<<dim3(KTOT / 64, DD / 64), 256, 0, stream>>>(d_queue, BhT);
  gather_A<<<P2, 256, 0, stream>>>(d_queue, dPSel, Apart, AhT);
  mfma_argmax<<<dim3(NPB, P2 / 128), 256, 0, stream>>>(AhT, BhT, dPosMem, pv2, pc2);
  argmax_rescore<<<P2, 256, 0, stream>>>(pv2, pc2, Apart, d_queue, dMemIdx, nval, nc);
  prep<<<P2 / 256, 256, 0, stream>>>(nc, nval, dMemIdx, dPSel, g_idx, svp, dp);
  gather_pne<<<DD, 256, 0, stream>>>(d_queue, g_idx, pneB);

  // Stage D: logits -> softmax -> structured-M epilogue (x2)
  gemm_f<<<dim3(PP / 128, BB / 128), 256, 0, stream>>>(d_student, pneB, F);
  softmax_out<<<BB, 256, 0, stream>>>(F, d_stemp, svp, dp, out);

  gemm_f<<<dim3(PP / 128, BB / 128), 256, 0, stream>>>(d_teacher, pneB, F);
  softmax_out<<<BB, 256, 0, stream>>>(F, d_ttemp, svp, dp, out + (size_t)BB * P2);
}